// Round 6
// baseline (269.241 us; speedup 1.0000x reference)
//
#include <hip/hip_runtime.h>
#include <cmath>

// Problem constants (from reference)
#define NB 4
#define NP 8192            // 2^13 points per batch
#define NE 262144          // 2^18 edges per batch
#define NCIN 32
#define NCOUT 32
#define NH 16
#define GAMMA 4.0f
#define NFEAT (NB * NP * NCIN)      // 1,048,576 floats (4 MB)
#define NOUT  (NB * NP * NCOUT)     // 1,048,576 floats (4 MB)
#define TILES_PER_BATCH (NE / 64)
#define NXCD 8

typedef _Float16 half8 __attribute__((ext_vector_type(8)));
typedef float floatx4 __attribute__((ext_vector_type(4)));

// ---------------------------------------------------------------------------
// Prep: zero the 8 per-XCD partial buffers (32 MB) + build f16 feature table.
// ---------------------------------------------------------------------------
__global__ __launch_bounds__(256)
void prep_kernel(const float* __restrict__ features,
                 _Float16* __restrict__ f16t,
                 floatx4* __restrict__ partial4)
{
    const int i = blockIdx.x * blockDim.x + threadIdx.x;    // 0 .. 262143
    const floatx4 z = {0.f, 0.f, 0.f, 0.f};
    #pragma unroll
    for (int k = 0; k < 8; ++k)                 // 8 x 4 MB, coalesced passes
        partial4[(long)k * 262144 + i] = z;

    if (i < NFEAT / 8) {                        // f32 -> f16 table
        const floatx4* src = (const floatx4*)features + (long)i * 2;
        floatx4 v0 = src[0], v1 = src[1];
        half8 h;
        h[0] = (_Float16)v0[0]; h[1] = (_Float16)v0[1];
        h[2] = (_Float16)v0[2]; h[3] = (_Float16)v0[3];
        h[4] = (_Float16)v1[0]; h[5] = (_Float16)v1[1];
        h[6] = (_Float16)v1[2]; h[7] = (_Float16)v1[3];
        *((half8*)f16t + i) = h;
    }
}

// cvt-only variant for the fallback path (no partial buffer).
__global__ __launch_bounds__(256)
void cvt_f16_kernel(const float* __restrict__ features, _Float16* __restrict__ f16t)
{
    const int i = blockIdx.x * blockDim.x + threadIdx.x;    // 0 .. 131071
    const floatx4* src = (const floatx4*)features + (long)i * 2;
    floatx4 v0 = src[0], v1 = src[1];
    half8 h;
    h[0] = (_Float16)v0[0]; h[1] = (_Float16)v0[1];
    h[2] = (_Float16)v0[2]; h[3] = (_Float16)v0[3];
    h[4] = (_Float16)v1[0]; h[5] = (_Float16)v1[1];
    h[6] = (_Float16)v1[2]; h[7] = (_Float16)v1[3];
    *((half8*)f16t + i) = h;
}

// ---------------------------------------------------------------------------
// Reduce: out = scale * sum_x partial[x].  Pure streaming (36 MB).
// ---------------------------------------------------------------------------
__global__ __launch_bounds__(256)
void reduce_kernel(const floatx4* __restrict__ partial4,
                   const int* __restrict__ n_norm_p,
                   floatx4* __restrict__ out4)
{
    const int i = blockIdx.x * blockDim.x + threadIdx.x;    // 0 .. 262143
    const int nn = n_norm_p[0];
    const float scale = (nn > 0) ? rsqrtf((float)nn) : 1.0f;
    floatx4 s = {0.f, 0.f, 0.f, 0.f};
    #pragma unroll
    for (int x = 0; x < NXCD; ++x)
        s += partial4[(long)x * 262144 + i];    // 4 MB stride = 2^18 float4
    out4[i] = s * scale;
}

// ---------------------------------------------------------------------------
// Main kernel: round-5 structure, but scatter goes to a PER-XCD partial
// buffer with XCD-LOCAL (L2-executed, no-sc1) atomics. xcc from
// s_getreg(HW_REG_XCC_ID) (HW-verified m09) -> correctness independent of
// block->XCD dispatch mapping. Per-XCD hot set: 1 MB partial + 512 KB f16
// features -> L2-resident; the 3.6 TB/s fabric wall disappears.
// scale is applied in reduce_kernel.
// ---------------------------------------------------------------------------
__global__ __launch_bounds__(256, 4)
void pconv_part_kernel(const _Float16* __restrict__ feat16,
                       const float* __restrict__ edge_vec,
                       const float* __restrict__ W,
                       const float* __restrict__ mu,
                       const int* __restrict__ edge_src,
                       const int* __restrict__ edge_dst,
                       float* __restrict__ partial)
{
    __shared__ _Float16 wsw[16 * 2 * 64 * 8];   // 32 KiB
    __shared__ float mus[16];

    const int tid = threadIdx.x;
    for (int idx = tid; idx < 16384; idx += 256) {
        int j = idx & 7;
        int l = (idx >> 3) & 63;
        int u = (idx >> 9) & 1;
        int s = idx >> 10;
        int n = (l & 15) + (u << 4);          // output channel o
        int i = ((l >> 4) << 3) | j;          // input channel
        wsw[idx] = (_Float16)W[(s * NCOUT + n) * NCIN + i];
    }
    if (tid < 16) mus[tid] = mu[tid];
    __syncthreads();

    // physical XCD id -> private partial buffer (4 MB = 2^20 floats)
    unsigned xcc;
    asm volatile("s_getreg_b32 %0, hwreg(HW_REG_XCC_ID)" : "=s"(xcc));
    float* pbase = partial + ((long)(xcc & 7) << 20);

    const int lane = tid & 63;
    const int wv   = tid >> 6;
    const int m    = lane & 15;   // A-row (edge) in main loop; D-col (channel) in epilogue
    const int q    = lane >> 4;

    // XCD-shard: group g = bid&7 -> batch g>>1, tile parity g&1 (perf-only).
    const int g    = blockIdx.x & 7;
    const int bb   = g >> 1;
    const int sub  = g & 1;
    const int bi   = blockIdx.x >> 3;        // 0..127 within group

    const _Float16* fbase = feat16 + ((long)bb << 13) * NCIN;
    float* obase = pbase + ((long)bb << 13) * NCOUT;
    const long ebatch = (long)bb * NE;

    for (int i = bi; i < TILES_PER_BATCH / 2; i += 128) {
        const int  tloc  = (i << 1) + sub;              // tile within batch
        const long ebase = ebatch + (long)tloc * 64 + (long)wv * 16;
        const long ge    = ebase + m;
        const int  src   = __builtin_nontemporal_load(edge_src + ge);

        // gather: one 64 B line per edge, L2-resident table; 16 B per lane
        half8 xh = *(const half8*)(fbase + (long)src * NCIN + q * 8);

        const float* ev = edge_vec + ge * 3;
        float vx = __builtin_nontemporal_load(ev + 0);
        float vy = __builtin_nontemporal_load(ev + 1);
        float vz = __builtin_nontemporal_load(ev + 2);
        // self-interaction zeroing in ref is a no-op numerically (r<1e-10 -> r=0)
        float r = sqrtf(vx * vx + vy * vy + vz * vz);

        float rbf[16];
        #pragma unroll
        for (int s = 0; s < 16; ++s) {
            float d = r - mus[s];
            rbf[s] = __expf(-GAMMA * d * d);
        }

        floatx4 accLo = {0.f, 0.f, 0.f, 0.f};   // channels 0..15
        floatx4 accHi = {0.f, 0.f, 0.f, 0.f};   // channels 16..31

        #pragma unroll
        for (int s = 0; s < 16; ++s) {
            const _Float16 rh = (_Float16)rbf[s];
            half8 a = xh * rh;                   // 4x v_pk_mul_f16
            half8 b0 = *(const half8*)(wsw + ((s * 2 + 0) * 64 + lane) * 8);
            half8 b1 = *(const half8*)(wsw + ((s * 2 + 1) * 64 + lane) * 8);
            accLo = __builtin_amdgcn_mfma_f32_16x16x32_f16(a, b0, accLo, 0, 0, 0);
            accHi = __builtin_amdgcn_mfma_f32_16x16x32_f16(a, b1, accHi, 0, 0, 0);
        }

        // Epilogue: XCD-local atomics into this XCD's private partial.
        #pragma unroll
        for (int rr = 0; rr < 4; ++rr) {
            const long e2  = ebase + q * 4 + rr;
            const int  dst = __builtin_nontemporal_load(edge_dst + e2);
            float* orow = obase + (long)dst * NCOUT;
            __hip_atomic_fetch_add(orow + m,      accLo[rr],
                                   __ATOMIC_RELAXED, __HIP_MEMORY_SCOPE_WORKGROUP);
            __hip_atomic_fetch_add(orow + m + 16, accHi[rr],
                                   __ATOMIC_RELAXED, __HIP_MEMORY_SCOPE_WORKGROUP);
        }
    }
}

// ---------------------------------------------------------------------------
// Fallback A (ws >= 2 MB): round-5 kernel verbatim (current best, 248 us).
// ---------------------------------------------------------------------------
__global__ __launch_bounds__(256, 4)
void pconv_f16_kernel(const _Float16* __restrict__ feat16,
                      const float* __restrict__ edge_vec,
                      const float* __restrict__ W,
                      const float* __restrict__ mu,
                      const int* __restrict__ edge_src,
                      const int* __restrict__ edge_dst,
                      const int* __restrict__ n_norm_p,
                      float* __restrict__ out)
{
    __shared__ _Float16 wsw[16 * 2 * 64 * 8];
    __shared__ float mus[16];

    const int tid = threadIdx.x;
    for (int idx = tid; idx < 16384; idx += 256) {
        int j = idx & 7;
        int l = (idx >> 3) & 63;
        int u = (idx >> 9) & 1;
        int s = idx >> 10;
        int n = (l & 15) + (u << 4);
        int i = ((l >> 4) << 3) | j;
        wsw[idx] = (_Float16)W[(s * NCOUT + n) * NCIN + i];
    }
    if (tid < 16) mus[tid] = mu[tid];
    __syncthreads();

    const int lane = tid & 63;
    const int wv   = tid >> 6;
    const int m    = lane & 15;
    const int q    = lane >> 4;

    const int nn = n_norm_p[0];
    const float scale = (nn > 0) ? rsqrtf((float)nn) : 1.0f;

    const int g    = blockIdx.x & 7;
    const int bb   = g >> 1;
    const int sub  = g & 1;
    const int bi   = blockIdx.x >> 3;

    const _Float16* fbase = feat16 + ((long)bb << 13) * NCIN;
    float* obase = out + ((long)bb << 13) * NCOUT;
    const long ebatch = (long)bb * NE;

    for (int i = bi; i < TILES_PER_BATCH / 2; i += 128) {
        const int  tloc  = (i << 1) + sub;
        const long ebase = ebatch + (long)tloc * 64 + (long)wv * 16;
        const long ge    = ebase + m;
        const int  src   = __builtin_nontemporal_load(edge_src + ge);

        half8 xh = *(const half8*)(fbase + (long)src * NCIN + q * 8);

        const float* ev = edge_vec + ge * 3;
        float vx = __builtin_nontemporal_load(ev + 0);
        float vy = __builtin_nontemporal_load(ev + 1);
        float vz = __builtin_nontemporal_load(ev + 2);
        float r = sqrtf(vx * vx + vy * vy + vz * vz);

        float rbf[16];
        #pragma unroll
        for (int s = 0; s < 16; ++s) {
            float d = r - mus[s];
            rbf[s] = __expf(-GAMMA * d * d);
        }

        floatx4 accLo = {0.f, 0.f, 0.f, 0.f};
        floatx4 accHi = {0.f, 0.f, 0.f, 0.f};

        #pragma unroll
        for (int s = 0; s < 16; ++s) {
            const _Float16 rh = (_Float16)rbf[s];
            half8 a = xh * rh;
            half8 b0 = *(const half8*)(wsw + ((s * 2 + 0) * 64 + lane) * 8);
            half8 b1 = *(const half8*)(wsw + ((s * 2 + 1) * 64 + lane) * 8);
            accLo = __builtin_amdgcn_mfma_f32_16x16x32_f16(a, b0, accLo, 0, 0, 0);
            accHi = __builtin_amdgcn_mfma_f32_16x16x32_f16(a, b1, accHi, 0, 0, 0);
        }

        #pragma unroll
        for (int rr = 0; rr < 4; ++rr) {
            const long e2  = ebase + q * 4 + rr;
            const int  dst = __builtin_nontemporal_load(edge_dst + e2);
            float* orow = obase + (long)dst * NCOUT;
            atomicAdd(orow + m,      accLo[rr] * scale);
            atomicAdd(orow + m + 16, accHi[rr] * scale);
        }
    }
}

// ---------------------------------------------------------------------------
// Fallback B (no workspace): round-3 kernel (f32 gathers).
// ---------------------------------------------------------------------------
__global__ __launch_bounds__(256, 4)
void pconv_mfma_kernel(const float* __restrict__ features,
                       const float* __restrict__ edge_vec,
                       const float* __restrict__ W,
                       const float* __restrict__ mu,
                       const int* __restrict__ edge_src,
                       const int* __restrict__ edge_dst,
                       const int* __restrict__ n_norm_p,
                       float* __restrict__ out)
{
    __shared__ _Float16 wsw[16 * 2 * 64 * 8];
    __shared__ float mus[16];

    const int tid = threadIdx.x;
    for (int idx = tid; idx < 16384; idx += 256) {
        int j = idx & 7;
        int l = (idx >> 3) & 63;
        int u = (idx >> 9) & 1;
        int s = idx >> 10;
        int n = (l & 15) + (u << 4);
        int i = ((l >> 4) << 3) | j;
        wsw[idx] = (_Float16)W[(s * NCOUT + n) * NCIN + i];
    }
    if (tid < 16) mus[tid] = mu[tid];
    __syncthreads();

    const int lane = tid & 63;
    const int wv   = tid >> 6;
    const int m    = lane & 15;
    const int q    = lane >> 4;

    const int nn = n_norm_p[0];
    const float scale = (nn > 0) ? rsqrtf((float)nn) : 1.0f;

    const int g    = blockIdx.x & 7;
    const int bb   = g >> 1;
    const int sub  = g & 1;
    const int bi   = blockIdx.x >> 3;

    const float* fbase = features + ((long)bb << 13) * NCIN;
    float* obase = out + ((long)bb << 13) * NCOUT;
    const long ebatch = (long)bb * NE;

    for (int i = bi; i < TILES_PER_BATCH / 2; i += 128) {
        const int  tloc  = (i << 1) + sub;
        const long ebase = ebatch + (long)tloc * 64 + (long)wv * 16;
        const long ge    = ebase + m;
        const int  src   = edge_src[ge];

        const float* xrow = fbase + (long)src * NCIN + q * 8;
        floatx4 xa = *(const floatx4*)(xrow);
        floatx4 xb = *(const floatx4*)(xrow + 4);

        const float* ev = edge_vec + ge * 3;
        float vx = ev[0], vy = ev[1], vz = ev[2];
        float r = sqrtf(vx * vx + vy * vy + vz * vz);

        float rbf[16];
        #pragma unroll
        for (int s = 0; s < 16; ++s) {
            float d = r - mus[s];
            rbf[s] = __expf(-GAMMA * d * d);
        }

        floatx4 accLo = {0.f, 0.f, 0.f, 0.f};
        floatx4 accHi = {0.f, 0.f, 0.f, 0.f};

        #pragma unroll
        for (int s = 0; s < 16; ++s) {
            const float rb = rbf[s];
            half8 a;
            a[0] = (_Float16)(rb * xa[0]);
            a[1] = (_Float16)(rb * xa[1]);
            a[2] = (_Float16)(rb * xa[2]);
            a[3] = (_Float16)(rb * xa[3]);
            a[4] = (_Float16)(rb * xb[0]);
            a[5] = (_Float16)(rb * xb[1]);
            a[6] = (_Float16)(rb * xb[2]);
            a[7] = (_Float16)(rb * xb[3]);
            half8 b0 = *(const half8*)(wsw + ((s * 2 + 0) * 64 + lane) * 8);
            half8 b1 = *(const half8*)(wsw + ((s * 2 + 1) * 64 + lane) * 8);
            accLo = __builtin_amdgcn_mfma_f32_16x16x32_f16(a, b0, accLo, 0, 0, 0);
            accHi = __builtin_amdgcn_mfma_f32_16x16x32_f16(a, b1, accHi, 0, 0, 0);
        }

        #pragma unroll
        for (int rr = 0; rr < 4; ++rr) {
            const long e2  = ebase + q * 4 + rr;
            const int  dst = edge_dst[e2];
            float* orow = obase + (long)dst * NCOUT;
            atomicAdd(orow + m,      accLo[rr] * scale);
            atomicAdd(orow + m + 16, accHi[rr] * scale);
        }
    }
}

extern "C" void kernel_launch(void* const* d_in, const int* in_sizes, int n_in,
                              void* d_out, int out_size, void* d_ws, size_t ws_size,
                              hipStream_t stream) {
    const float* features = (const float*)d_in[0];
    const float* edge_vec = (const float*)d_in[1];
    const float* W        = (const float*)d_in[2];
    const float* mu       = (const float*)d_in[3];
    const int*   edge_src = (const int*)d_in[4];
    const int*   edge_dst = (const int*)d_in[5];
    const int*   n_norm   = (const int*)d_in[6];
    float* out = (float*)d_out;

    // ws layout (full path): partial[8][4 MB] | f16 table (2 MB)
    const size_t part_bytes = (size_t)NXCD * NOUT * sizeof(float);   // 32 MB
    const size_t f16_bytes  = (size_t)NFEAT * sizeof(_Float16);      //  2 MB
    const size_t need_full  = part_bytes + f16_bytes;

    if (d_ws != nullptr && ws_size >= need_full) {
        float*    partial = (float*)d_ws;
        _Float16* f16t    = (_Float16*)((char*)d_ws + part_bytes);

        prep_kernel<<<1024, 256, 0, stream>>>(features, f16t, (floatx4*)partial);
        // grid MUST be 1024: 8 XCD groups x 128 blocks; 4 blocks/CU.
        pconv_part_kernel<<<1024, 256, 0, stream>>>(f16t, edge_vec, W, mu,
                                                    edge_src, edge_dst, partial);
        reduce_kernel<<<1024, 256, 0, stream>>>((const floatx4*)partial, n_norm,
                                                (floatx4*)out);
    } else if (d_ws != nullptr && ws_size >= f16_bytes) {
        hipMemsetAsync(out, 0, (size_t)out_size * sizeof(float), stream);
        _Float16* f16t = (_Float16*)d_ws;
        cvt_f16_kernel<<<NFEAT / 8 / 256, 256, 0, stream>>>(features, f16t);
        pconv_f16_kernel<<<1024, 256, 0, stream>>>(f16t, edge_vec, W, mu,
                                                   edge_src, edge_dst, n_norm, out);
    } else {
        hipMemsetAsync(out, 0, (size_t)out_size * sizeof(float), stream);
        pconv_mfma_kernel<<<1024, 256, 0, stream>>>(features, edge_vec, W, mu,
                                                    edge_src, edge_dst, n_norm, out);
    }
}